// Round 2
// baseline (131.464 us; speedup 1.0000x reference)
//
#include <hip/hip_runtime.h>

#define NB 16
#define NS 4096
#define CHUNK 240            // output tokens per block (256 threads - 16 halo)
#define NCHUNK 18            // ceil(4096/240)
#define NBLK (NB * NCHUNK)   // 288

// out[b,s,:] = (sum_{u=s-8..s+8 clipped} relu((x+pe)[b,u]@W1 + b1)) @ (Wv@W2) + b2
// weights  = all ones (softmax over a singleton axis) -- Wq, Wk are dead code
__global__ __launch_bounds__(256) void fused_kernel(
    const float* __restrict__ x,
    const float* __restrict__ pe,
    const float* __restrict__ w1p,
    const float* __restrict__ b1p,
    const float* __restrict__ wvp,
    const float* __restrict__ w2p,
    const float* __restrict__ b2p,
    float* __restrict__ out,
    float* __restrict__ wts)
{
    __shared__ float W1T[64][64];   // W1T[d][i] = W1[i][d]
    __shared__ float MT[2][64];     // MT[o][d]  = sum_j Wv[d][j]*W2[j][o]
    __shared__ float B1[64];
    __shared__ float PL[256][2];    // p values for tokens s0-8 .. s0+247

    const int tid = threadIdx.x;
    const int blk = blockIdx.x;
    const int b   = blk / NCHUNK;
    const int s0  = (blk % NCHUNK) * CHUNK;

    // ---- stage small weights into LDS ----
    #pragma unroll
    for (int k = 0; k < 16; ++k) {
        int e = k * 256 + tid;                 // 0..4095
        int d = e >> 6, i = e & 63;
        W1T[d][i] = w1p[i * 64 + d];           // transpose; 16KB, L2-resident
    }
    if (tid < 64) B1[tid] = b1p[tid];
    if (tid >= 64 && tid < 192) {
        int t = tid - 64;
        int o = t >> 6, d = t & 63;
        float acc = 0.f;
        #pragma unroll 8
        for (int j = 0; j < 64; ++j)
            acc = fmaf(wvp[d * 64 + j], w2p[j * 2 + o], acc);
        MT[o][d] = acc;
    }
    __syncthreads();

    // ---- per-thread token: p[sp] = relu((x+pe)@W1 + b1) @ M ----
    const int sp = s0 - 8 + tid;
    float p0 = 0.f, p1 = 0.f;
    if ((unsigned)sp < (unsigned)NS) {
        const size_t base = (((size_t)b * NS) + (size_t)sp) * 64;
        const float4* xa = (const float4*)(x + base);
        const float4* pa = (const float4*)(pe + base);
        float xr[64];
        #pragma unroll
        for (int c = 0; c < 16; ++c) {
            float4 xv = xa[c];
            float4 pv = pa[c];
            xr[4*c + 0] = xv.x + pv.x;
            xr[4*c + 1] = xv.y + pv.y;
            xr[4*c + 2] = xv.z + pv.z;
            xr[4*c + 3] = xv.w + pv.w;
        }
        #pragma unroll 4
        for (int d = 0; d < 64; ++d) {
            float a0 = B1[d], a1 = 0.f, a2 = 0.f, a3 = 0.f;
            #pragma unroll
            for (int i = 0; i < 64; i += 16) {
                const float4 wa = *(const float4*)&W1T[d][i];
                const float4 wb = *(const float4*)&W1T[d][i + 4];
                const float4 wc = *(const float4*)&W1T[d][i + 8];
                const float4 wd = *(const float4*)&W1T[d][i + 12];
                a0 = fmaf(xr[i +  0], wa.x, a0);
                a0 = fmaf(xr[i +  1], wa.y, a0);
                a0 = fmaf(xr[i +  2], wa.z, a0);
                a0 = fmaf(xr[i +  3], wa.w, a0);
                a1 = fmaf(xr[i +  4], wb.x, a1);
                a1 = fmaf(xr[i +  5], wb.y, a1);
                a1 = fmaf(xr[i +  6], wb.z, a1);
                a1 = fmaf(xr[i +  7], wb.w, a1);
                a2 = fmaf(xr[i +  8], wc.x, a2);
                a2 = fmaf(xr[i +  9], wc.y, a2);
                a2 = fmaf(xr[i + 10], wc.z, a2);
                a2 = fmaf(xr[i + 11], wc.w, a2);
                a3 = fmaf(xr[i + 12], wd.x, a3);
                a3 = fmaf(xr[i + 13], wd.y, a3);
                a3 = fmaf(xr[i + 14], wd.z, a3);
                a3 = fmaf(xr[i + 15], wd.w, a3);
            }
            float h = fmaxf((a0 + a1) + (a2 + a3), 0.f);
            p0 = fmaf(h, MT[0][d], p0);
            p1 = fmaf(h, MT[1][d], p1);
        }
    }
    PL[tid][0] = p0;
    PL[tid][1] = p1;
    __syncthreads();

    // ---- sliding-window sum (±8) + b2, write out ----
    if (tid >= 8 && tid < 8 + CHUNK && sp < NS) {
        float o0 = 0.f, o1 = 0.f;
        #pragma unroll
        for (int w = 0; w < 17; ++w) {
            o0 += PL[tid - 8 + w][0];
            o1 += PL[tid - 8 + w][1];
        }
        float2 r;
        r.x = o0 + b2p[0];
        r.y = o1 + b2p[1];
        *((float2*)(out + (((size_t)b * NS) + (size_t)sp) * 2)) = r;
    }

    // ---- weights output: all ones (softmax over singleton axis) ----
    {
        float4* wp = (float4*)wts;
        const unsigned int total_v = (NB * NS * 17) / 4;   // 278528 float4s
        const float4 one4 = make_float4(1.f, 1.f, 1.f, 1.f);
        for (unsigned int idx = (unsigned int)blk * 256u + (unsigned int)tid;
             idx < total_v; idx += (unsigned int)NBLK * 256u) {
            wp[idx] = one4;
        }
    }
}

extern "C" void kernel_launch(void* const* d_in, const int* in_sizes, int n_in,
                              void* d_out, int out_size, void* d_ws, size_t ws_size,
                              hipStream_t stream) {
    const float* x  = (const float*)d_in[0];
    const float* pe = (const float*)d_in[1];
    const float* w1 = (const float*)d_in[2];
    const float* b1 = (const float*)d_in[3];
    // d_in[4] = Wq, d_in[5] = Wk: dead (softmax over singleton axis => weights==1)
    const float* wv = (const float*)d_in[6];
    const float* w2 = (const float*)d_in[7];
    const float* b2 = (const float*)d_in[8];

    float* out = (float*)d_out;                       // (B,S,2) = 131072 floats
    float* wts = out + (size_t)NB * NS * 2;           // (B,S,1,17) = 1114112 floats

    fused_kernel<<<NBLK, 256, 0, stream>>>(x, pe, w1, b1, wv, w2, b2, out, wts);
}

// Round 3
// 110.898 us; speedup vs baseline: 1.1854x; 1.1854x over previous
//
#include <hip/hip_runtime.h>

#define NB 16
#define NS 4096
#define NTOK (NB * NS)         // 65536 tokens
#define TPB 32                 // tokens per A-block
#define ABLK (NTOK / TPB)      // 2048 blocks
#define BBLK 512               // out_kernel blocks

// p[token] = relu((x+pe)[token] @ W1 + b1) @ (Wv @ W2)   (per-token, no window)
// d-split 8-way: thread (token, dg) computes d = dg*8 .. dg*8+7
__global__ __launch_bounds__(256, 4) void p_kernel(
    const float* __restrict__ x,
    const float* __restrict__ pe,
    const float* __restrict__ w1p,
    const float* __restrict__ b1p,
    const float* __restrict__ wvp,
    const float* __restrict__ w2p,
    float* __restrict__ pws)
{
    __shared__ float W1T[64][68];   // W1T[d][i] = W1[i][d]; 68: 16B-aligned rows
    __shared__ float XS[TPB][68];   // (x+pe)[token][i]
    __shared__ float MT[2][64];     // M^T[o][d] = (Wv@W2)[d][o]
    __shared__ float B1[64];
    __shared__ float W2S[128];      // W2 row-major [64][2]
    __shared__ float2 PP[8][TPB];   // per-dgroup partial p

    const int tid = threadIdx.x;
    const int blk = blockIdx.x;

    // ---- stage W2 (for M compute), W1 transposed, x+pe, b1 ----
    if (tid < 128) W2S[tid] = w2p[tid];

    const float4* w14 = (const float4*)w1p;          // 1024 float4
    #pragma unroll
    for (int k = 0; k < 4; ++k) {
        int f4 = k * 256 + tid;
        int i  = f4 >> 4;             // W1 row (input feature)
        int d0 = (f4 & 15) * 4;       // W1 col (hidden)
        float4 v = w14[f4];
        W1T[d0 + 0][i] = v.x;
        W1T[d0 + 1][i] = v.y;
        W1T[d0 + 2][i] = v.z;
        W1T[d0 + 3][i] = v.w;
    }
    {
        const size_t base4 = (size_t)blk * (TPB * 64 / 4);   // 512 float4 per block
        const float4* xa = (const float4*)x + base4;
        const float4* pa = (const float4*)pe + base4;
        #pragma unroll
        for (int q = 0; q < 2; ++q) {
            int f4 = q * 256 + tid;
            int t  = f4 >> 4;
            int d0 = (f4 & 15) * 4;
            float4 xv = xa[f4];
            float4 pv = pa[f4];
            float4 s;
            s.x = xv.x + pv.x; s.y = xv.y + pv.y;
            s.z = xv.z + pv.z; s.w = xv.w + pv.w;
            *(float4*)&XS[t][d0] = s;
        }
    }
    if (tid >= 128 && tid < 192) B1[tid - 128] = b1p[tid - 128];
    __syncthreads();

    // ---- MT[o][d] = sum_j Wv[d][j] * W2[j][o]  (threads 0..127) ----
    if (tid < 128) {
        const int o = tid & 1, d = tid >> 1;
        const float4* wv4 = (const float4*)(wvp + d * 64);   // Wv row d
        float m0 = 0.f, m1 = 0.f, m2 = 0.f, m3 = 0.f;
        #pragma unroll
        for (int j4 = 0; j4 < 16; j4 += 4) {
            float4 a = wv4[j4 + 0];
            float4 b = wv4[j4 + 1];
            float4 c = wv4[j4 + 2];
            float4 e = wv4[j4 + 3];
            int jb = j4 * 4;
            m0 = fmaf(a.x, W2S[(jb +  0)*2 + o], m0);
            m0 = fmaf(a.y, W2S[(jb +  1)*2 + o], m0);
            m0 = fmaf(a.z, W2S[(jb +  2)*2 + o], m0);
            m0 = fmaf(a.w, W2S[(jb +  3)*2 + o], m0);
            m1 = fmaf(b.x, W2S[(jb +  4)*2 + o], m1);
            m1 = fmaf(b.y, W2S[(jb +  5)*2 + o], m1);
            m1 = fmaf(b.z, W2S[(jb +  6)*2 + o], m1);
            m1 = fmaf(b.w, W2S[(jb +  7)*2 + o], m1);
            m2 = fmaf(c.x, W2S[(jb +  8)*2 + o], m2);
            m2 = fmaf(c.y, W2S[(jb +  9)*2 + o], m2);
            m2 = fmaf(c.z, W2S[(jb + 10)*2 + o], m2);
            m2 = fmaf(c.w, W2S[(jb + 11)*2 + o], m2);
            m3 = fmaf(e.x, W2S[(jb + 12)*2 + o], m3);
            m3 = fmaf(e.y, W2S[(jb + 13)*2 + o], m3);
            m3 = fmaf(e.z, W2S[(jb + 14)*2 + o], m3);
            m3 = fmaf(e.w, W2S[(jb + 15)*2 + o], m3);
        }
        MT[o][d] = (m0 + m1) + (m2 + m3);
    }
    __syncthreads();

    // ---- matvec: thread (token = tid&31, dg = tid>>5) ----
    const int token = tid & 31;
    const int dg    = tid >> 5;
    const int d0    = dg * 8;

    float4 xq[16];
    #pragma unroll
    for (int i = 0; i < 16; ++i) xq[i] = *(const float4*)&XS[token][4 * i];

    float p0 = 0.f, p1 = 0.f;
    #pragma unroll 2
    for (int dd = 0; dd < 8; ++dd) {
        const int d = d0 + dd;
        float a0 = B1[d], a1 = 0.f, a2 = 0.f, a3 = 0.f;
        #pragma unroll
        for (int i4 = 0; i4 < 16; i4 += 4) {
            float4 wa = *(const float4*)&W1T[d][4 * (i4 + 0)];
            float4 wb = *(const float4*)&W1T[d][4 * (i4 + 1)];
            float4 wc = *(const float4*)&W1T[d][4 * (i4 + 2)];
            float4 wd = *(const float4*)&W1T[d][4 * (i4 + 3)];
            float4 x0 = xq[i4 + 0], x1 = xq[i4 + 1], x2 = xq[i4 + 2], x3 = xq[i4 + 3];
            a0 = fmaf(x0.x, wa.x, a0); a0 = fmaf(x0.y, wa.y, a0);
            a0 = fmaf(x0.z, wa.z, a0); a0 = fmaf(x0.w, wa.w, a0);
            a1 = fmaf(x1.x, wb.x, a1); a1 = fmaf(x1.y, wb.y, a1);
            a1 = fmaf(x1.z, wb.z, a1); a1 = fmaf(x1.w, wb.w, a1);
            a2 = fmaf(x2.x, wc.x, a2); a2 = fmaf(x2.y, wc.y, a2);
            a2 = fmaf(x2.z, wc.z, a2); a2 = fmaf(x2.w, wc.w, a2);
            a3 = fmaf(x3.x, wd.x, a3); a3 = fmaf(x3.y, wd.y, a3);
            a3 = fmaf(x3.z, wd.z, a3); a3 = fmaf(x3.w, wd.w, a3);
        }
        float h = fmaxf((a0 + a1) + (a2 + a3), 0.f);
        p0 = fmaf(h, MT[0][d], p0);
        p1 = fmaf(h, MT[1][d], p1);
    }
    PP[dg][token] = make_float2(p0, p1);
    __syncthreads();

    // ---- reduce 8 partials per token, write p to workspace ----
    if (tid < TPB) {
        float2 s = PP[0][tid];
        #pragma unroll
        for (int g = 1; g < 8; ++g) {
            float2 t = PP[g][tid];
            s.x += t.x; s.y += t.y;
        }
        ((float2*)pws)[blk * TPB + tid] = s;
    }
}

// out[g,c] = b2[c] + sum_{w=-8..8, 0<=s+w<NS} p[g+w][c]; weights = 1.0
__global__ __launch_bounds__(256) void out_kernel(
    const float* __restrict__ pws,
    const float* __restrict__ b2p,
    float* __restrict__ out,
    float* __restrict__ wts)
{
    const int gid = blockIdx.x * 256 + threadIdx.x;   // 0..131071
    const int g = gid >> 1, c = gid & 1;
    const int s = g & (NS - 1);

    float acc = b2p[c];
    #pragma unroll
    for (int w = -8; w <= 8; ++w) {
        int ss = s + w;
        if (0 <= ss && ss < NS) acc += pws[gid + 2 * w];
    }
    out[gid] = acc;

    float4* wp = (float4*)wts;
    const float4 one4 = make_float4(1.f, 1.f, 1.f, 1.f);
    const unsigned total_v = (NB * NS * 17) / 4;      // 278528
    for (unsigned idx = (unsigned)gid; idx < total_v; idx += BBLK * 256)
        wp[idx] = one4;
}

extern "C" void kernel_launch(void* const* d_in, const int* in_sizes, int n_in,
                              void* d_out, int out_size, void* d_ws, size_t ws_size,
                              hipStream_t stream) {
    const float* x  = (const float*)d_in[0];
    const float* pe = (const float*)d_in[1];
    const float* w1 = (const float*)d_in[2];
    const float* b1 = (const float*)d_in[3];
    // d_in[4]=Wq, d_in[5]=Wk: dead (softmax over singleton axis => weights==1)
    const float* wv = (const float*)d_in[6];
    const float* w2 = (const float*)d_in[7];
    const float* b2 = (const float*)d_in[8];

    float* out = (float*)d_out;                 // (B,S,2) = 131072 floats
    float* wts = out + (size_t)NB * NS * 2;     // (B,S,1,17) = 1114112 floats
    float* pws = (float*)d_ws;                  // 65536 * 2 floats = 512 KB scratch

    p_kernel<<<ABLK, 256, 0, stream>>>(x, pe, w1, b1, wv, w2, pws);
    out_kernel<<<BBLK, 256, 0, stream>>>(pws, b2, out, wts);
}

// Round 5
// 103.715 us; speedup vs baseline: 1.2675x; 1.0693x over previous
//
#include <hip/hip_runtime.h>

#define NB 16
#define NS 4096
#define NTOK (NB * NS)         // 65536 tokens
#define TOKB 128               // tokens per block
#define ABLK (NTOK / TOKB)     // 512 blocks
#define BBLK 256               // out_kernel blocks
#define WTS_V ((NB * NS * 17) / 4)   // 278528 float4 of weights

// p[token] = relu((x+pe)[token] @ W1 + b1) @ (Wv @ W2)
// thread = (tg, dg): 4 tokens (4tg..4tg+3) x 8 hidden dims (8dg..8dg+7)
__global__ __launch_bounds__(256, 2) void p_kernel(
    const float* __restrict__ x,
    const float* __restrict__ pe,
    const float* __restrict__ w1p,
    const float* __restrict__ b1p,
    const float* __restrict__ wvp,
    const float* __restrict__ w2p,
    float* __restrict__ pws,
    float* __restrict__ wts)
{
    __shared__ __align__(16) float W1T[64][68];    // W1T[d][i] = W1[i][d]
    __shared__ __align__(16) float XST[64][132];   // XST[i][t] = (x+pe)[tok0+t][i]
    __shared__ float MT[2][64];                    // (Wv@W2)^T
    __shared__ float B1[64];
    __shared__ float W2S[128];
    __shared__ float2 PP[8][128];                  // per-dg partial p

    const int tid = threadIdx.x;
    const int blk = blockIdx.x;

    // ---- issue bulk global loads up front (hide latency) ----
    const float4* xa = (const float4*)x  + (size_t)blk * (TOKB * 16);
    const float4* pa = (const float4*)pe + (size_t)blk * (TOKB * 16);
    float4 xv[8], pv[8], w1v[4];
    #pragma unroll
    for (int q = 0; q < 8; ++q) xv[q] = xa[q * 256 + tid];
    #pragma unroll
    for (int q = 0; q < 8; ++q) pv[q] = pa[q * 256 + tid];
    const float4* w14 = (const float4*)w1p;
    #pragma unroll
    for (int k = 0; k < 4; ++k) w1v[k] = w14[k * 256 + tid];
    if (tid < 128) W2S[tid] = w2p[tid];
    if (tid >= 128 && tid < 192) B1[tid - 128] = b1p[tid - 128];

    // ---- scatter W1 (transposed) and x+pe (transposed) into LDS ----
    #pragma unroll
    for (int k = 0; k < 4; ++k) {
        int f4 = k * 256 + tid;
        int i = f4 >> 4, c = f4 & 15;
        W1T[4*c+0][i] = w1v[k].x;
        W1T[4*c+1][i] = w1v[k].y;
        W1T[4*c+2][i] = w1v[k].z;
        W1T[4*c+3][i] = w1v[k].w;
    }
    #pragma unroll
    for (int q = 0; q < 8; ++q) {
        int f4 = q * 256 + tid;
        int t = f4 >> 4, c = f4 & 15;
        XST[4*c+0][t] = xv[q].x + pv[q].x;
        XST[4*c+1][t] = xv[q].y + pv[q].y;
        XST[4*c+2][t] = xv[q].z + pv[q].z;
        XST[4*c+3][t] = xv[q].w + pv[q].w;
    }
    __syncthreads();

    // ---- MT[o][d] = sum_j Wv[d][j] * W2[j][o]  (Wv is L2-hot, 16KB) ----
    if (tid < 128) {
        const int o = tid & 1, d = tid >> 1;
        const float4* wv4 = (const float4*)(wvp + (size_t)d * 64);
        float m0 = 0.f, m1 = 0.f, m2 = 0.f, m3 = 0.f;
        #pragma unroll
        for (int j4 = 0; j4 < 16; j4 += 4) {
            float4 a = wv4[j4 + 0], b = wv4[j4 + 1], c = wv4[j4 + 2], e = wv4[j4 + 3];
            int jb = j4 * 4;
            m0 = fmaf(a.x, W2S[(jb+ 0)*2+o], m0); m0 = fmaf(a.y, W2S[(jb+ 1)*2+o], m0);
            m0 = fmaf(a.z, W2S[(jb+ 2)*2+o], m0); m0 = fmaf(a.w, W2S[(jb+ 3)*2+o], m0);
            m1 = fmaf(b.x, W2S[(jb+ 4)*2+o], m1); m1 = fmaf(b.y, W2S[(jb+ 5)*2+o], m1);
            m1 = fmaf(b.z, W2S[(jb+ 6)*2+o], m1); m1 = fmaf(b.w, W2S[(jb+ 7)*2+o], m1);
            m2 = fmaf(c.x, W2S[(jb+ 8)*2+o], m2); m2 = fmaf(c.y, W2S[(jb+ 9)*2+o], m2);
            m2 = fmaf(c.z, W2S[(jb+10)*2+o], m2); m2 = fmaf(c.w, W2S[(jb+11)*2+o], m2);
            m3 = fmaf(e.x, W2S[(jb+12)*2+o], m3); m3 = fmaf(e.y, W2S[(jb+13)*2+o], m3);
            m3 = fmaf(e.z, W2S[(jb+14)*2+o], m3); m3 = fmaf(e.w, W2S[(jb+15)*2+o], m3);
        }
        MT[o][d] = (m0 + m1) + (m2 + m3);
    }
    __syncthreads();

    // ---- matvec: 4 tokens x 8 dims per thread, W reused across tokens ----
    const int tg = tid & 31;        // tokens 4tg .. 4tg+3
    const int dg = tid >> 5;        // dims 8dg .. 8dg+7
    float4 acc[8];
    #pragma unroll
    for (int dd = 0; dd < 8; ++dd) acc[dd] = make_float4(0.f, 0.f, 0.f, 0.f);

    #pragma unroll 2
    for (int i = 0; i < 64; i += 4) {
        float4 xw0 = *(const float4*)&XST[i + 0][4 * tg];
        float4 xw1 = *(const float4*)&XST[i + 1][4 * tg];
        float4 xw2 = *(const float4*)&XST[i + 2][4 * tg];
        float4 xw3 = *(const float4*)&XST[i + 3][4 * tg];
        #pragma unroll
        for (int dd = 0; dd < 8; ++dd) {
            const float4 w = *(const float4*)&W1T[8 * dg + dd][i];
            acc[dd].x = fmaf(w.x, xw0.x, acc[dd].x);
            acc[dd].y = fmaf(w.x, xw0.y, acc[dd].y);
            acc[dd].z = fmaf(w.x, xw0.z, acc[dd].z);
            acc[dd].w = fmaf(w.x, xw0.w, acc[dd].w);
            acc[dd].x = fmaf(w.y, xw1.x, acc[dd].x);
            acc[dd].y = fmaf(w.y, xw1.y, acc[dd].y);
            acc[dd].z = fmaf(w.y, xw1.z, acc[dd].z);
            acc[dd].w = fmaf(w.y, xw1.w, acc[dd].w);
            acc[dd].x = fmaf(w.z, xw2.x, acc[dd].x);
            acc[dd].y = fmaf(w.z, xw2.y, acc[dd].y);
            acc[dd].z = fmaf(w.z, xw2.z, acc[dd].z);
            acc[dd].w = fmaf(w.z, xw2.w, acc[dd].w);
            acc[dd].x = fmaf(w.w, xw3.x, acc[dd].x);
            acc[dd].y = fmaf(w.w, xw3.y, acc[dd].y);
            acc[dd].z = fmaf(w.w, xw3.z, acc[dd].z);
            acc[dd].w = fmaf(w.w, xw3.w, acc[dd].w);
        }
    }

    float4 p0 = make_float4(0.f,0.f,0.f,0.f), p1 = make_float4(0.f,0.f,0.f,0.f);
    #pragma unroll
    for (int dd = 0; dd < 8; ++dd) {
        const int d = 8 * dg + dd;
        const float bb = B1[d];
        float4 h;
        h.x = fmaxf(acc[dd].x + bb, 0.f);
        h.y = fmaxf(acc[dd].y + bb, 0.f);
        h.z = fmaxf(acc[dd].z + bb, 0.f);
        h.w = fmaxf(acc[dd].w + bb, 0.f);
        const float m0 = MT[0][d], m1 = MT[1][d];
        p0.x = fmaf(h.x, m0, p0.x); p0.y = fmaf(h.y, m0, p0.y);
        p0.z = fmaf(h.z, m0, p0.z); p0.w = fmaf(h.w, m0, p0.w);
        p1.x = fmaf(h.x, m1, p1.x); p1.y = fmaf(h.y, m1, p1.y);
        p1.z = fmaf(h.z, m1, p1.z); p1.w = fmaf(h.w, m1, p1.w);
    }
    PP[dg][4*tg+0] = make_float2(p0.x, p1.x);
    PP[dg][4*tg+1] = make_float2(p0.y, p1.y);
    PP[dg][4*tg+2] = make_float2(p0.z, p1.z);
    PP[dg][4*tg+3] = make_float2(p0.w, p1.w);
    __syncthreads();

    // ---- reduce 8 partials, write p (conflict-free: consecutive words) ----
    {
        const float* pp = (const float*)PP;
        float s = 0.f;
        #pragma unroll
        for (int g = 0; g < 8; ++g) s += pp[g * 256 + tid];
        pws[(size_t)blk * 256 + tid] = s;
    }

    // ---- weights = 1.0 fill (overlaps other blocks' compute) ----
    {
        float4* wp = (float4*)wts;
        const float4 one4 = make_float4(1.f, 1.f, 1.f, 1.f);
        for (unsigned idx = (unsigned)blk * 256u + (unsigned)tid;
             idx < WTS_V; idx += (unsigned)ABLK * 256u)
            wp[idx] = one4;
    }
}

// out[g,c] = b2[c] + sum_{w=-8..8, 0<=s+w<NS} p[g+w][c]
__global__ __launch_bounds__(256) void out_kernel(
    const float* __restrict__ pws,
    const float* __restrict__ b2p,
    float* __restrict__ out)
{
    const int gid = blockIdx.x * 256 + threadIdx.x;
    for (int g2 = gid; g2 < NTOK * 2; g2 += BBLK * 256) {
        const int g = g2 >> 1, c = g2 & 1;
        const int s = g & (NS - 1);
        float acc = b2p[c];
        #pragma unroll
        for (int w = -8; w <= 8; ++w) {
            int ss = s + w;
            if (0 <= ss && ss < NS) acc += pws[g2 + 2 * w];
        }
        out[g2] = acc;
    }
}

extern "C" void kernel_launch(void* const* d_in, const int* in_sizes, int n_in,
                              void* d_out, int out_size, void* d_ws, size_t ws_size,
                              hipStream_t stream) {
    const float* x  = (const float*)d_in[0];
    const float* pe = (const float*)d_in[1];
    const float* w1 = (const float*)d_in[2];
    const float* b1 = (const float*)d_in[3];
    // d_in[4]=Wq, d_in[5]=Wk: dead (softmax over singleton axis => weights==1)
    const float* wv = (const float*)d_in[6];
    const float* w2 = (const float*)d_in[7];
    const float* b2 = (const float*)d_in[8];

    float* out = (float*)d_out;                 // (B,S,2) = 131072 floats
    float* wts = out + (size_t)NB * NS * 2;     // (B,S,1,17) = 1114112 floats
    float* pws = (float*)d_ws;                  // 65536 * 2 floats

    p_kernel<<<ABLK, 256, 0, stream>>>(x, pe, w1, b1, wv, w2, pws, wts);
    out_kernel<<<BBLK, 256, 0, stream>>>(pws, b2, out);
}

// Round 6
// 101.475 us; speedup vs baseline: 1.2955x; 1.0221x over previous
//
#include <hip/hip_runtime.h>

#define NB 16
#define NS 4096
#define NTOK (NB * NS)         // 65536 tokens
#define TOKB 64                // tokens per p-block
#define ABLK (NTOK / TOKB)     // 1024 blocks
#define OBLK 256               // out_kernel blocks (256*256 = 65536 = NTOK)
#define WTS_V ((NB * NS * 17) / 4)   // 278528 float4 of weights

// p[token] = relu((x+pe)[token] @ W1 + b1) @ (Wv @ W2)
// 256 threads = 16 tg x 16 dg; thread does 4 tokens (4tg..) x 4 dims (4dg..)
// LDS ~44KB -> 3 blocks/CU -> 3 waves/SIMD (vs 2 in prior round)
__global__ __launch_bounds__(256, 3) void p_kernel(
    const float* __restrict__ x,
    const float* __restrict__ pe,
    const float* __restrict__ w1p,
    const float* __restrict__ b1p,
    const float* __restrict__ wvp,
    const float* __restrict__ w2p,
    float* __restrict__ pws,
    float* __restrict__ wts)
{
    __shared__ __align__(16) float W1T[64][68];   // W1T[d][i] = W1[i][d]
    __shared__ __align__(16) float XST[64][68];   // XST[i][t] = (x+pe)[tok0+t][i]
    __shared__ float MT[2][64];                   // (Wv@W2)^T
    __shared__ float B1[64];
    __shared__ float W2S[128];
    __shared__ float PP[16][128];                 // per-dg partial p (float2/token)

    const int tid = threadIdx.x;
    const int blk = blockIdx.x;

    // ---- staged global loads (12 float4 per thread) ----
    const float4* w14 = (const float4*)w1p;       // 1024 float4 of W1
    const float4* xa  = (const float4*)x  + (size_t)blk * (TOKB * 16);
    const float4* pa  = (const float4*)pe + (size_t)blk * (TOKB * 16);
    float4 w1v[4], xv[4], pv[4];
    #pragma unroll
    for (int k = 0; k < 4; ++k) w1v[k] = w14[k * 256 + tid];
    #pragma unroll
    for (int q = 0; q < 4; ++q) xv[q] = xa[q * 256 + tid];
    #pragma unroll
    for (int q = 0; q < 4; ++q) pv[q] = pa[q * 256 + tid];
    if (tid < 128) W2S[tid] = w2p[tid];
    if (tid >= 128 && tid < 192) B1[tid - 128] = b1p[tid - 128];

    // ---- scatter W1 (transposed) and x+pe (transposed) into LDS ----
    #pragma unroll
    for (int k = 0; k < 4; ++k) {
        int f4 = k * 256 + tid;
        int i = f4 >> 4, c = f4 & 15;
        W1T[4*c+0][i] = w1v[k].x;
        W1T[4*c+1][i] = w1v[k].y;
        W1T[4*c+2][i] = w1v[k].z;
        W1T[4*c+3][i] = w1v[k].w;
    }
    #pragma unroll
    for (int q = 0; q < 4; ++q) {
        int f4 = q * 256 + tid;
        int t = f4 >> 4, c = f4 & 15;     // t: 0..63
        XST[4*c+0][t] = xv[q].x + pv[q].x;
        XST[4*c+1][t] = xv[q].y + pv[q].y;
        XST[4*c+2][t] = xv[q].z + pv[q].z;
        XST[4*c+3][t] = xv[q].w + pv[q].w;
    }
    __syncthreads();

    // ---- MT[o][d] = sum_j Wv[d][j] * W2[j][o]  (Wv 16KB, L2-hot) ----
    if (tid < 128) {
        const int o = tid & 1, d = tid >> 1;
        const float4* wv4 = (const float4*)(wvp + (size_t)d * 64);
        float m0 = 0.f, m1 = 0.f, m2 = 0.f, m3 = 0.f;
        #pragma unroll
        for (int j4 = 0; j4 < 16; j4 += 4) {
            float4 a = wv4[j4 + 0], b = wv4[j4 + 1], c = wv4[j4 + 2], e = wv4[j4 + 3];
            int jb = j4 * 4;
            m0 = fmaf(a.x, W2S[(jb+ 0)*2+o], m0); m0 = fmaf(a.y, W2S[(jb+ 1)*2+o], m0);
            m0 = fmaf(a.z, W2S[(jb+ 2)*2+o], m0); m0 = fmaf(a.w, W2S[(jb+ 3)*2+o], m0);
            m1 = fmaf(b.x, W2S[(jb+ 4)*2+o], m1); m1 = fmaf(b.y, W2S[(jb+ 5)*2+o], m1);
            m1 = fmaf(b.z, W2S[(jb+ 6)*2+o], m1); m1 = fmaf(b.w, W2S[(jb+ 7)*2+o], m1);
            m2 = fmaf(c.x, W2S[(jb+ 8)*2+o], m2); m2 = fmaf(c.y, W2S[(jb+ 9)*2+o], m2);
            m2 = fmaf(c.z, W2S[(jb+10)*2+o], m2); m2 = fmaf(c.w, W2S[(jb+11)*2+o], m2);
            m3 = fmaf(e.x, W2S[(jb+12)*2+o], m3); m3 = fmaf(e.y, W2S[(jb+13)*2+o], m3);
            m3 = fmaf(e.z, W2S[(jb+14)*2+o], m3); m3 = fmaf(e.w, W2S[(jb+15)*2+o], m3);
        }
        MT[o][d] = (m0 + m1) + (m2 + m3);
    }
    __syncthreads();

    // ---- matvec: 4 tokens x 4 dims per thread ----
    const int tg = tid & 15;        // tokens 4tg .. 4tg+3
    const int dg = tid >> 4;        // dims 4dg .. 4dg+3
    float4 acc[4];
    #pragma unroll
    for (int dd = 0; dd < 4; ++dd) acc[dd] = make_float4(0.f, 0.f, 0.f, 0.f);

    #pragma unroll 4
    for (int i = 0; i < 64; i += 4) {
        float4 xw0 = *(const float4*)&XST[i + 0][4 * tg];
        float4 xw1 = *(const float4*)&XST[i + 1][4 * tg];
        float4 xw2 = *(const float4*)&XST[i + 2][4 * tg];
        float4 xw3 = *(const float4*)&XST[i + 3][4 * tg];
        #pragma unroll
        for (int dd = 0; dd < 4; ++dd) {
            const float4 w = *(const float4*)&W1T[4 * dg + dd][i];
            acc[dd].x = fmaf(w.x, xw0.x, acc[dd].x);
            acc[dd].y = fmaf(w.x, xw0.y, acc[dd].y);
            acc[dd].z = fmaf(w.x, xw0.z, acc[dd].z);
            acc[dd].w = fmaf(w.x, xw0.w, acc[dd].w);
            acc[dd].x = fmaf(w.y, xw1.x, acc[dd].x);
            acc[dd].y = fmaf(w.y, xw1.y, acc[dd].y);
            acc[dd].z = fmaf(w.y, xw1.z, acc[dd].z);
            acc[dd].w = fmaf(w.y, xw1.w, acc[dd].w);
            acc[dd].x = fmaf(w.z, xw2.x, acc[dd].x);
            acc[dd].y = fmaf(w.z, xw2.y, acc[dd].y);
            acc[dd].z = fmaf(w.z, xw2.z, acc[dd].z);
            acc[dd].w = fmaf(w.z, xw2.w, acc[dd].w);
            acc[dd].x = fmaf(w.w, xw3.x, acc[dd].x);
            acc[dd].y = fmaf(w.w, xw3.y, acc[dd].y);
            acc[dd].z = fmaf(w.w, xw3.z, acc[dd].z);
            acc[dd].w = fmaf(w.w, xw3.w, acc[dd].w);
        }
    }

    // ---- epilogue: relu + project through MT, write partials ----
    float4 p0 = make_float4(0.f,0.f,0.f,0.f), p1 = make_float4(0.f,0.f,0.f,0.f);
    #pragma unroll
    for (int dd = 0; dd < 4; ++dd) {
        const int d = 4 * dg + dd;
        const float bb = B1[d];
        float4 h;
        h.x = fmaxf(acc[dd].x + bb, 0.f);
        h.y = fmaxf(acc[dd].y + bb, 0.f);
        h.z = fmaxf(acc[dd].z + bb, 0.f);
        h.w = fmaxf(acc[dd].w + bb, 0.f);
        const float m0 = MT[0][d], m1 = MT[1][d];
        p0.x = fmaf(h.x, m0, p0.x); p0.y = fmaf(h.y, m0, p0.y);
        p0.z = fmaf(h.z, m0, p0.z); p0.w = fmaf(h.w, m0, p0.w);
        p1.x = fmaf(h.x, m1, p1.x); p1.y = fmaf(h.y, m1, p1.y);
        p1.z = fmaf(h.z, m1, p1.z); p1.w = fmaf(h.w, m1, p1.w);
    }
    *(float2*)&PP[dg][2*(4*tg+0)] = make_float2(p0.x, p1.x);
    *(float2*)&PP[dg][2*(4*tg+1)] = make_float2(p0.y, p1.y);
    *(float2*)&PP[dg][2*(4*tg+2)] = make_float2(p0.z, p1.z);
    *(float2*)&PP[dg][2*(4*tg+3)] = make_float2(p0.w, p1.w);
    __syncthreads();

    // ---- reduce 16 partials, write p (128 outputs per block) ----
    if (tid < 128) {
        float s = 0.f;
        #pragma unroll
        for (int g = 0; g < 16; ++g) s += PP[g][tid];
        pws[(size_t)blk * 128 + tid] = s;
    }

    // ---- weights = 1.0 fill (overlaps across blocks) ----
    {
        float4* wp = (float4*)wts;
        const float4 one4 = make_float4(1.f, 1.f, 1.f, 1.f);
        for (unsigned idx = (unsigned)blk * 256u + (unsigned)tid;
             idx < WTS_V; idx += (unsigned)ABLK * 256u)
            wp[idx] = one4;
    }
}

// out[g,:] = b2 + sum_{w=-8..8, 0<=s+w<NS} p[g+w][:]   (one thread per token)
__global__ __launch_bounds__(256) void out_kernel(
    const float* __restrict__ pws,
    const float* __restrict__ b2p,
    float* __restrict__ out)
{
    const int g = blockIdx.x * 256 + threadIdx.x;     // 0..65535
    const int s = g & (NS - 1);
    const float2* p2 = (const float2*)pws;
    float ax = b2p[0], ay = b2p[1];
    #pragma unroll
    for (int w = -8; w <= 8; ++w) {
        int ss = s + w;
        if (0 <= ss && ss < NS) {
            float2 v = p2[g + w];
            ax += v.x; ay += v.y;
        }
    }
    ((float2*)out)[g] = make_float2(ax, ay);
}

extern "C" void kernel_launch(void* const* d_in, const int* in_sizes, int n_in,
                              void* d_out, int out_size, void* d_ws, size_t ws_size,
                              hipStream_t stream) {
    const float* x  = (const float*)d_in[0];
    const float* pe = (const float*)d_in[1];
    const float* w1 = (const float*)d_in[2];
    const float* b1 = (const float*)d_in[3];
    // d_in[4]=Wq, d_in[5]=Wk: dead (softmax over singleton axis => weights==1)
    const float* wv = (const float*)d_in[6];
    const float* w2 = (const float*)d_in[7];
    const float* b2 = (const float*)d_in[8];

    float* out = (float*)d_out;                 // (B,S,2) = 131072 floats
    float* wts = out + (size_t)NB * NS * 2;     // (B,S,1,17) = 1114112 floats
    float* pws = (float*)d_ws;                  // 65536 * 2 floats

    p_kernel<<<ABLK, 256, 0, stream>>>(x, pe, w1, b1, wv, w2, pws, wts);
    out_kernel<<<OBLK, 256, 0, stream>>>(pws, b2, out);
}

// Round 7
// 93.706 us; speedup vs baseline: 1.4029x; 1.0829x over previous
//
#include <hip/hip_runtime.h>

#define NS 4096
#define NTOK 65536            // 16 * 4096 tokens
#define TOKB 128              // output tokens per block
#define GRID 512              // NTOK / TOKB
#define NTILE 9               // (TOKB + 2*8) / 16 token-tiles incl halo
#define WTS_V 278528u         // (16*4096*17)/4 float4 of weights
#define F4MAX 1048575         // NTOK*16 - 1 (flat float4 index clamp)

typedef __attribute__((ext_vector_type(8))) short bfrag;   // 8 bf16 = 4 VGPR
typedef __attribute__((ext_vector_type(4))) float f32x4;

__device__ __forceinline__ unsigned short f2bf(float f) {
    union { unsigned int i; float f; } c; c.f = f;
    unsigned int u = c.i;
    unsigned int r = u + 0x7FFFu + ((u >> 16) & 1u);   // RNE
    return (unsigned short)(r >> 16);
}

// out[b,s,:] = (sum_{u=s-8..s+8 in-batch} relu((x+pe)[b,u]@W1 + b1)) @ (Wv@W2) + b2
// weights = all ones (softmax over singleton axis; Wq/Wk dead).
// h-GEMM in bf16 MFMA (fp32 accum); everything else fp32.
__global__ __launch_bounds__(256, 2) void fused(
    const float* __restrict__ x, const float* __restrict__ pe,
    const float* __restrict__ w1p, const float* __restrict__ b1p,
    const float* __restrict__ wvp, const float* __restrict__ w2p,
    const float* __restrict__ b2p,
    float* __restrict__ out, float* __restrict__ wts)
{
    __shared__ bfrag Xb[144 * 8];   // (x+pe) bf16, 144 tokens x 64, row-swizzled
    __shared__ bfrag Wf[512];       // W1 bf16 B-fragments [kh][dtile][lane]
    __shared__ float B1s[64], M0s[64], M1s[64], W2S[128];
    __shared__ float PL[146][2];    // p per local token (144 used)

    const int tid  = threadIdx.x;
    const int blk  = blockIdx.x;
    const int lane = tid & 63;
    const int wid  = tid >> 6;

    // ---- stage Xb: tokens g0-8 .. g0+135 as bf16, 16B chunks XOR-swizzled ----
    const int gbase4 = blk * 2048 - 128;           // float4 idx of token g0-8
    const float4* x4 = (const float4*)x;
    const float4* p4 = (const float4*)pe;
    #pragma unroll
    for (int it = 0; it < 5; ++it) {
        int cidx = it * 256 + tid;                 // chunk = 8 bf16 of one token
        if (cidx < 1152) {
            int f0 = gbase4 + cidx * 2, f1 = f0 + 1;
            f0 = f0 < 0 ? 0 : (f0 > F4MAX ? F4MAX : f0);
            f1 = f1 < 0 ? 0 : (f1 > F4MAX ? F4MAX : f1);
            float4 a = x4[f0], b = x4[f1], c = p4[f0], d = p4[f1];
            union { unsigned short u[8]; bfrag v; } P;
            P.u[0] = f2bf(a.x + c.x); P.u[1] = f2bf(a.y + c.y);
            P.u[2] = f2bf(a.z + c.z); P.u[3] = f2bf(a.w + c.w);
            P.u[4] = f2bf(b.x + d.x); P.u[5] = f2bf(b.y + d.y);
            P.u[6] = f2bf(b.z + d.z); P.u[7] = f2bf(b.w + d.w);
            int tl = cidx >> 3;
            int sc = (cidx & 7) ^ (tl & 7);        // bank-spread chunks
            Xb[tl * 8 + sc] = P.v;
        }
    }
    // ---- stage Wf: B-operand fragments of W1 (k=(l>>4)*8+j+32kh, col=l&15) ----
    #pragma unroll
    for (int s = 0; s < 2; ++s) {
        int slot = s * 256 + tid;                  // 0..511
        int kh = slot >> 8, rem = slot & 255, dt = rem >> 6, l = rem & 63;
        int dd = dt * 16 + (l & 15);
        int kb = kh * 32 + ((l >> 4) << 3);
        union { unsigned short u[8]; bfrag v; } P;
        #pragma unroll
        for (int j = 0; j < 8; ++j) P.u[j] = f2bf(w1p[(kb + j) * 64 + dd]);
        Wf[slot] = P.v;
    }
    if (tid < 64) B1s[tid] = b1p[tid];
    if (tid >= 64 && tid < 192) W2S[tid - 64] = w2p[tid - 64];
    __syncthreads();

    // ---- M = Wv @ W2 (fp32), 128 threads ----
    if (tid < 128) {
        const int o = tid & 1, dd = tid >> 1;
        const float4* wv4 = (const float4*)(wvp + (size_t)dd * 64);
        float m0 = 0.f, m1 = 0.f, m2 = 0.f, m3 = 0.f;
        #pragma unroll
        for (int j4 = 0; j4 < 16; j4 += 4) {
            float4 a = wv4[j4 + 0], b = wv4[j4 + 1], c = wv4[j4 + 2], e = wv4[j4 + 3];
            int jb = j4 * 4;
            m0 = fmaf(a.x, W2S[(jb+ 0)*2+o], m0); m0 = fmaf(a.y, W2S[(jb+ 1)*2+o], m0);
            m0 = fmaf(a.z, W2S[(jb+ 2)*2+o], m0); m0 = fmaf(a.w, W2S[(jb+ 3)*2+o], m0);
            m1 = fmaf(b.x, W2S[(jb+ 4)*2+o], m1); m1 = fmaf(b.y, W2S[(jb+ 5)*2+o], m1);
            m1 = fmaf(b.z, W2S[(jb+ 6)*2+o], m1); m1 = fmaf(b.w, W2S[(jb+ 7)*2+o], m1);
            m2 = fmaf(c.x, W2S[(jb+ 8)*2+o], m2); m2 = fmaf(c.y, W2S[(jb+ 9)*2+o], m2);
            m2 = fmaf(c.z, W2S[(jb+10)*2+o], m2); m2 = fmaf(c.w, W2S[(jb+11)*2+o], m2);
            m3 = fmaf(e.x, W2S[(jb+12)*2+o], m3); m3 = fmaf(e.y, W2S[(jb+13)*2+o], m3);
            m3 = fmaf(e.z, W2S[(jb+14)*2+o], m3); m3 = fmaf(e.w, W2S[(jb+15)*2+o], m3);
        }
        float v = (m0 + m1) + (m2 + m3);
        if (o) M1s[dd] = v; else M0s[dd] = v;
    }
    __syncthreads();

    // ---- MFMA: per wave, token-tiles tau = wid, wid+4, wid+8 ----
    const int cl = lane & 15;                      // col within d-tile
    float biasv[4], m0v[4], m1v[4];
    #pragma unroll
    for (int dt = 0; dt < 4; ++dt) {
        biasv[dt] = B1s[dt * 16 + cl];
        m0v[dt]   = M0s[dt * 16 + cl];
        m1v[dt]   = M1s[dt * 16 + cl];
    }
    const int sbase = (blk & 31) * 128 - 8;        // in-batch index of local tok 0
    for (int tau = wid; tau < NTILE; tau += 4) {
        float pr0[4] = {0.f,0.f,0.f,0.f}, pr1[4] = {0.f,0.f,0.f,0.f};
        const int arow = (tau * 16 + cl) * 8;
        #pragma unroll
        for (int dt = 0; dt < 4; ++dt) {
            f32x4 acc = {0.f, 0.f, 0.f, 0.f};
            #pragma unroll
            for (int kh = 0; kh < 2; ++kh) {
                bfrag av = Xb[arow + (((kh << 2) + (lane >> 4)) ^ (lane & 7))];
                bfrag bv = Wf[(kh * 4 + dt) * 64 + lane];
                acc = __builtin_amdgcn_mfma_f32_16x16x32_bf16(av, bv, acc, 0, 0, 0);
            }
            #pragma unroll
            for (int rg = 0; rg < 4; ++rg) {       // D: col=lane&15, row=(lane>>4)*4+rg
                float h = fmaxf(acc[rg] + biasv[dt], 0.f);
                pr0[rg] = fmaf(h, m0v[dt], pr0[rg]);
                pr1[rg] = fmaf(h, m1v[dt], pr1[rg]);
            }
        }
        #pragma unroll
        for (int rg = 0; rg < 4; ++rg) {           // reduce over 16 col-lanes
            #pragma unroll
            for (int m = 1; m < 16; m <<= 1) {
                pr0[rg] += __shfl_xor(pr0[rg], m);
                pr1[rg] += __shfl_xor(pr1[rg], m);
            }
        }
        if ((lane & 15) == 0) {
            const int rgrp = lane >> 4;
            #pragma unroll
            for (int rg = 0; rg < 4; ++rg) {
                int tl = tau * 16 + rgrp * 4 + rg;
                bool valid = (unsigned)(sbase + tl) < 4096u;  // batch-window mask
                PL[tl][0] = valid ? pr0[rg] : 0.f;
                PL[tl][1] = valid ? pr1[rg] : 0.f;
            }
        }
    }
    __syncthreads();

    // ---- window sum (+/-8) + b2, write out ----
    if (tid < 128) {
        float ax = b2p[0], ay = b2p[1];
        #pragma unroll
        for (int k = 0; k <= 16; ++k) {
            float2 v = *(const float2*)&PL[tid + k][0];
            ax += v.x; ay += v.y;
        }
        ((float2*)out)[(size_t)blk * 128 + tid] = make_float2(ax, ay);
    }

    // ---- weights = 1.0 ----
    {
        float4* wp = (float4*)wts;
        const float4 one4 = make_float4(1.f, 1.f, 1.f, 1.f);
        for (unsigned idx = (unsigned)blk * 256u + (unsigned)tid;
             idx < WTS_V; idx += (unsigned)GRID * 256u)
            wp[idx] = one4;
    }
}

extern "C" void kernel_launch(void* const* d_in, const int* in_sizes, int n_in,
                              void* d_out, int out_size, void* d_ws, size_t ws_size,
                              hipStream_t stream) {
    const float* x  = (const float*)d_in[0];
    const float* pe = (const float*)d_in[1];
    const float* w1 = (const float*)d_in[2];
    const float* b1 = (const float*)d_in[3];
    // d_in[4]=Wq, d_in[5]=Wk: dead (softmax over singleton axis => weights==1)
    const float* wv = (const float*)d_in[6];
    const float* w2 = (const float*)d_in[7];
    const float* b2 = (const float*)d_in[8];

    float* out = (float*)d_out;                 // (B,S,2) = 131072 floats
    float* wts = out + (size_t)NTOK * 2;        // (B,S,1,17) = 1114112 floats

    fused<<<GRID, 256, 0, stream>>>(x, pe, w1, b1, wv, w2, b2, out, wts);
}